// Round 1
// 545.214 us; speedup vs baseline: 1.9579x; 1.9579x over previous
//
#include <hip/hip_runtime.h>
#include <hip/hip_bf16.h>

#define N_S 1024
#define N_R 768
#define LN_EPS 1e-5f
#define MEAN_EPS 1e-10f
#define LARGE_F 1e9f
#define QSCALE 0.35355339059327373f  // 8^-0.5

typedef __attribute__((ext_vector_type(8))) __bf16 bf16x8;
typedef __attribute__((ext_vector_type(4))) float f32x4;

__device__ __forceinline__ float bflo(unsigned u){ union{unsigned v; float f;} x; x.v = u << 16; return x.f; }
__device__ __forceinline__ unsigned short f2b(float f){
  __hip_bfloat16 h = __float2bfloat16(f);
  return *reinterpret_cast<unsigned short*>(&h);
}
__device__ __forceinline__ unsigned pk2(float a, float b){
  return (unsigned)f2b(a) | ((unsigned)f2b(b) << 16);
}
__device__ __forceinline__ bf16x8 ld_frag(const void* p){
  uint4 u = *reinterpret_cast<const uint4*>(p);
  return __builtin_bit_cast(bf16x8, u);
}

// ============ kernel 1: LN + K/V proj + masked-q + softmax -> wavg; block N_R does weight prep ============
struct SharedS { _Float16 kv[N_S][16]; };  // [s][0..7]=k, [s][8..15]=v  (32 KiB)

__global__ __launch_bounds__(256, 2) void stats_kernel(
    const float* __restrict__ act, const float* __restrict__ mask,
    const float* __restrict__ lns, const float* __restrict__ lnb,
    const float* __restrict__ qw,  const float* __restrict__ kw,
    const float* __restrict__ vw,  const float* __restrict__ gw,
    const float* __restrict__ ow,  float* __restrict__ wavg_out,
    uint4* __restrict__ wsf)
{
  __shared__ SharedS sh;
  __shared__ float redA[4][64];
  __shared__ float redB[4][8];
  __shared__ float q_lds[64];
  __shared__ float qf_lds[64];

  const int tid  = threadIdx.x;
  const int lane = tid & 63;
  const int wave = tid >> 6;
  const int r    = blockIdx.x;

  if (r >= N_R) {
    // ---- weight fragment prep: bf16 hi/lo fragments for gw (A=gw^T) and ow (A=ow^T) ----
    // layout: wsf[(m*8 + mf*2 + ks)*64 + lane], m: 0=gw_hi 1=gw_lo 2=ow_hi 3=ow_lo
    #pragma unroll 1
    for (int rep = 0; rep < 2; rep++) {
      int fi = wave + rep * 4;              // 0..7
      int mf = fi >> 1, ks = fi & 1;
      int g = lane >> 4, c15 = lane & 15;
      union { uint4 u; unsigned short h[8]; } ghi, glo, ohi, olo;
      #pragma unroll
      for (int t = 0; t < 8; t++) {
        int k = ks * 32 + g * 8 + t;        // contraction index
        float gv = gw[k * 64 + mf * 16 + c15];   // A1[j=mf*16+c15][c=k] = gw[c][j]
        unsigned short gh = f2b(gv);
        ghi.h[t] = gh;
        glo.h[t] = f2b(gv - bflo(gh));
        float ov = ow[k * 64 + mf * 16 + c15];   // A2[o=mf*16+c15][j=k] = ow[j][o]
        unsigned short oh = f2b(ov);
        ohi.h[t] = oh;
        olo.h[t] = f2b(ov - bflo(oh));
      }
      wsf[(0 * 8 + fi) * 64 + lane] = ghi.u;
      wsf[(1 * 8 + fi) * 64 + lane] = glo.u;
      wsf[(2 * 8 + fi) * 64 + lane] = ohi.u;
      wsf[(3 * 8 + fi) * 64 + lane] = olo.u;
    }
    return;
  }

  // ================= pass 1: LN + k/v projections + masked q-sum =================
  float qacc[64];
  #pragma unroll
  for (int c = 0; c < 64; c++) qacc[c] = 0.f;
  float msum = 0.f;

  #pragma unroll 1
  for (int it = 0; it < 4; it++) {
    int s = tid + it * 256;
    size_t base = ((size_t)s * N_R + r) * 64;
    float rw[64];
    const float4* rp = reinterpret_cast<const float4*>(act + base);
    #pragma unroll
    for (int i = 0; i < 16; i++) reinterpret_cast<float4*>(rw)[i] = rp[i];

    float m = mask[(size_t)s * N_R + r];

    float sum = 0.f, ss = 0.f;
    #pragma unroll
    for (int c = 0; c < 64; c++) { sum += rw[c]; ss += rw[c] * rw[c]; }
    float mu  = sum * (1.f / 64.f);
    float var = ss * (1.f / 64.f) - mu * mu;
    float rsd = rsqrtf(var + LN_EPS);

    float kacc[8], vacc[8];
    #pragma unroll
    for (int d = 0; d < 8; d++) { kacc[d] = 0.f; vacc[d] = 0.f; }

    #pragma unroll
    for (int c = 0; c < 64; c++) {
      float xn = fmaf((rw[c] - mu) * rsd, lns[c], lnb[c]);
      qacc[c] = fmaf(m, xn, qacc[c]);
      #pragma unroll
      for (int d = 0; d < 8; d++) {
        kacc[d] = fmaf(xn, kw[c * 8 + d], kacc[d]);
        vacc[d] = fmaf(xn, vw[c * 8 + d], vacc[d]);
      }
    }
    union { uint4 u; _Float16 h[8]; } kb, vb;
    #pragma unroll
    for (int d = 0; d < 8; d++) { kb.h[d] = (_Float16)kacc[d]; vb.h[d] = (_Float16)vacc[d]; }
    *reinterpret_cast<uint4*>(&sh.kv[s][0]) = kb.u;
    *reinterpret_cast<uint4*>(&sh.kv[s][8]) = vb.u;
    msum += m;
  }

  #pragma unroll
  for (int c = 0; c < 64; c++) {
    #pragma unroll
    for (int o = 32; o > 0; o >>= 1) qacc[c] += __shfl_xor(qacc[c], o);
  }
  #pragma unroll
  for (int o = 32; o > 0; o >>= 1) msum += __shfl_xor(msum, o);
  if (lane == 0) {
    redB[wave][0] = msum;
    #pragma unroll
    for (int c = 0; c < 64; c++) redA[wave][c] = qacc[c];
  }
  __syncthreads();
  if (tid < 64) {
    float qs = redA[0][tid] + redA[1][tid] + redA[2][tid] + redA[3][tid];
    float mt = redB[0][0] + redB[1][0] + redB[2][0] + redB[3][0];
    q_lds[tid] = qs / (mt + MEAN_EPS);
  }
  __syncthreads();
  if (tid < 64) {
    float acc = 0.f;
    for (int c = 0; c < 64; c++) acc = fmaf(q_lds[c], qw[c * 64 + tid], acc);
    qf_lds[tid] = acc * QSCALE;
  }
  __syncthreads();

  // ================= softmax over s (per head) + weighted_avg =================
  float qreg[64];
  #pragma unroll
  for (int j = 0; j < 64; j++) qreg[j] = qf_lds[j];

  float ev[4][8];
  float hm[8];
  #pragma unroll
  for (int h = 0; h < 8; h++) hm[h] = -1e30f;

  #pragma unroll
  for (int it = 0; it < 4; it++) {
    int s = tid + it * 256;
    union { uint4 u; _Float16 h[8]; } kb;
    kb.u = *reinterpret_cast<uint4*>(&sh.kv[s][0]);
    float kk[8];
    #pragma unroll
    for (int d = 0; d < 8; d++) kk[d] = (float)kb.h[d];
    float m = mask[(size_t)s * N_R + r];
    float bias = LARGE_F * (m - 1.f);
    #pragma unroll
    for (int h = 0; h < 8; h++) {
      float l = bias;
      #pragma unroll
      for (int d = 0; d < 8; d++) l = fmaf(qreg[h * 8 + d], kk[d], l);
      ev[it][h] = l;
      hm[h] = fmaxf(hm[h], l);
    }
  }
  #pragma unroll
  for (int h = 0; h < 8; h++) {
    #pragma unroll
    for (int o = 32; o > 0; o >>= 1) hm[h] = fmaxf(hm[h], __shfl_xor(hm[h], o));
  }
  if (lane == 0) {
    #pragma unroll
    for (int h = 0; h < 8; h++) redB[wave][h] = hm[h];
  }
  __syncthreads();
  #pragma unroll
  for (int h = 0; h < 8; h++)
    hm[h] = fmaxf(fmaxf(redB[0][h], redB[1][h]), fmaxf(redB[2][h], redB[3][h]));
  __syncthreads();  // redB reused for sums

  float hs[8];
  #pragma unroll
  for (int h = 0; h < 8; h++) hs[h] = 0.f;
  #pragma unroll
  for (int it = 0; it < 4; it++) {
    #pragma unroll
    for (int h = 0; h < 8; h++) {
      float e = __expf(ev[it][h] - hm[h]);
      ev[it][h] = e;
      hs[h] += e;
    }
  }
  #pragma unroll
  for (int h = 0; h < 8; h++) {
    #pragma unroll
    for (int o = 32; o > 0; o >>= 1) hs[h] += __shfl_xor(hs[h], o);
  }
  if (lane == 0) {
    #pragma unroll
    for (int h = 0; h < 8; h++) redB[wave][h] = hs[h];
  }
  __syncthreads();

  float wacc[64];
  #pragma unroll
  for (int j = 0; j < 64; j++) wacc[j] = 0.f;
  #pragma unroll
  for (int it = 0; it < 4; it++) {
    int s = tid + it * 256;
    union { uint4 u; _Float16 h[8]; } vb;
    vb.u = *reinterpret_cast<uint4*>(&sh.kv[s][8]);
    float vv[8];
    #pragma unroll
    for (int d = 0; d < 8; d++) vv[d] = (float)vb.h[d];
    #pragma unroll
    for (int h = 0; h < 8; h++) {
      float w = ev[it][h];
      #pragma unroll
      for (int d = 0; d < 8; d++) wacc[h * 8 + d] = fmaf(w, vv[d], wacc[h * 8 + d]);
    }
  }
  #pragma unroll
  for (int j = 0; j < 64; j++) {
    #pragma unroll
    for (int o = 32; o > 0; o >>= 1) wacc[j] += __shfl_xor(wacc[j], o);
  }
  if (lane == 0) {
    #pragma unroll
    for (int j = 0; j < 64; j++) redA[wave][j] = wacc[j];
  }
  __syncthreads();
  if (tid < 64) {
    int h = tid >> 3;
    float hsv = redB[0][h] + redB[1][h] + redB[2][h] + redB[3][h];
    wavg_out[r * 64 + tid] =
        (redA[0][tid] + redA[1][tid] + redA[2][tid] + redA[3][tid]) / hsv;
  }
}

// ============ kernel 2: LN + gate GEMM + sigmoid*wavg + output GEMM (MFMA) ============
// grid: 768 r * 16 s-blocks; block = 4 waves, each wave owns 16 s-rows.
// GEMM1 (swapped): G[j][s] = sum_c gw[c][j] * x[s][c]   (A=gw^T, B=x^T)
// GEMM2 (swapped): out[o][s] = sum_j ow[j][o] * coef[j][s] (A=ow^T, B=coef^T)
__global__ __launch_bounds__(256, 2) void proj_kernel(
    const float* __restrict__ act, const float* __restrict__ lns,
    const float* __restrict__ lnb, const float* __restrict__ gb,
    const float* __restrict__ ob,  const float* __restrict__ wavg,
    const uint4* __restrict__ wsf, float* __restrict__ out)
{
  __shared__ uint4 wfrag[32][64];            // 32 KiB weight fragments (shared by all waves)
  __shared__ __align__(16) char wbuf[4][4096]; // per-wave staging (x / coef / out, sequential lifetimes)

  const int tid  = threadIdx.x;
  const int lane = tid & 63;
  const int wv   = tid >> 6;
  const int r    = blockIdx.x >> 4;
  const int s0   = ((blockIdx.x & 15) << 6) + wv * 16;

  {
    uint4* dst = &wfrag[0][0];
    #pragma unroll
    for (int i = 0; i < 8; i++) dst[tid + i * 256] = wsf[tid + i * 256];
  }
  __syncthreads();

  char* my = wbuf[wv];
  const int qr = lane >> 2, qc = lane & 3;   // row-within-tile, quad column

  const size_t rowbase = ((size_t)(s0 + qr) * N_R + r) * 64;

  // ---- load 16 f32 (interleaved float4s of one row) + LN over quad ----
  float rv[16];
  {
    const float4* ap = reinterpret_cast<const float4*>(act + rowbase);
    #pragma unroll
    for (int i = 0; i < 4; i++)
      *reinterpret_cast<float4*>(&rv[4 * i]) = ap[qc + 4 * i];
  }
  float sum = 0.f, ssq = 0.f;
  #pragma unroll
  for (int j = 0; j < 16; j++) { sum += rv[j]; ssq += rv[j] * rv[j]; }
  sum += __shfl_xor(sum, 1); ssq += __shfl_xor(ssq, 1);
  sum += __shfl_xor(sum, 2); ssq += __shfl_xor(ssq, 2);
  float mu  = sum * (1.f / 64.f);
  float rsd = rsqrtf(ssq * (1.f / 64.f) - mu * mu + LN_EPS);

  // ---- normalize -> bf16 -> LDS x-tile in B-frag order: [c>>3][s][c&7] ----
  #pragma unroll
  for (int i = 0; i < 4; i++) {
    int c0 = 16 * i + 4 * qc;
    float4 s4 = *reinterpret_cast<const float4*>(lns + c0);
    float4 b4 = *reinterpret_cast<const float4*>(lnb + c0);
    float x0 = fmaf((rv[4*i+0] - mu) * rsd, s4.x, b4.x);
    float x1 = fmaf((rv[4*i+1] - mu) * rsd, s4.y, b4.y);
    float x2 = fmaf((rv[4*i+2] - mu) * rsd, s4.z, b4.z);
    float x3 = fmaf((rv[4*i+3] - mu) * rsd, s4.w, b4.w);
    uint2 p; p.x = pk2(x0, x1); p.y = pk2(x2, x3);
    int byt = ((2 * i + (qc >> 1)) << 8) + (qr << 4) + ((qc & 1) << 3);
    *reinterpret_cast<uint2*>(my + byt) = p;
  }
  asm volatile("" ::: "memory");
  // B-frag read is linear: lane l -> byte l*16  (conflict-free ds_read_b128)
  bf16x8 xb0 = ld_frag(my + lane * 16);
  bf16x8 xb1 = ld_frag(my + 1024 + lane * 16);

  const f32x4 zero = {0.f, 0.f, 0.f, 0.f};
  f32x4 acc[4] = {zero, zero, zero, zero};
  #pragma unroll
  for (int mf = 0; mf < 4; mf++) {
    acc[mf] = __builtin_amdgcn_mfma_f32_16x16x32_bf16(ld_frag(&wfrag[     mf*2    ][lane]), xb0, acc[mf], 0, 0, 0);
    acc[mf] = __builtin_amdgcn_mfma_f32_16x16x32_bf16(ld_frag(&wfrag[ 8 + mf*2    ][lane]), xb0, acc[mf], 0, 0, 0);
    acc[mf] = __builtin_amdgcn_mfma_f32_16x16x32_bf16(ld_frag(&wfrag[     mf*2 + 1][lane]), xb1, acc[mf], 0, 0, 0);
    acc[mf] = __builtin_amdgcn_mfma_f32_16x16x32_bf16(ld_frag(&wfrag[ 8 + mf*2 + 1][lane]), xb1, acc[mf], 0, 0, 0);
  }

  // ---- coef = wavg[j] * sigmoid(G + gb[j]) -> bf16 -> LDS in B-frag order ----
  const int g = lane >> 4, c15 = lane & 15;
  asm volatile("" ::: "memory");
  #pragma unroll
  for (int mf = 0; mf < 4; mf++) {
    int jb = mf * 16 + 4 * g;                 // j of acc regs 0..3; s = c15
    float4 wv4 = *reinterpret_cast<const float4*>(wavg + r * 64 + jb);
    float4 gb4 = *reinterpret_cast<const float4*>(gb + jb);
    float c0 = wv4.x / (1.f + __expf(-(acc[mf][0] + gb4.x)));
    float c1 = wv4.y / (1.f + __expf(-(acc[mf][1] + gb4.y)));
    float c2 = wv4.z / (1.f + __expf(-(acc[mf][2] + gb4.z)));
    float c3 = wv4.w / (1.f + __expf(-(acc[mf][3] + gb4.w)));
    uint2 p; p.x = pk2(c0, c1); p.y = pk2(c2, c3);
    int byt = 2048 + ((2 * mf + (g >> 1)) << 8) + (c15 << 4) + ((g & 1) << 3);
    *reinterpret_cast<uint2*>(my + byt) = p;
  }
  asm volatile("" ::: "memory");
  bf16x8 cb0 = ld_frag(my + 2048 + lane * 16);
  bf16x8 cb1 = ld_frag(my + 3072 + lane * 16);

  f32x4 acc2[4] = {zero, zero, zero, zero};
  #pragma unroll
  for (int mf = 0; mf < 4; mf++) {
    acc2[mf] = __builtin_amdgcn_mfma_f32_16x16x32_bf16(ld_frag(&wfrag[16 + mf*2    ][lane]), cb0, acc2[mf], 0, 0, 0);
    acc2[mf] = __builtin_amdgcn_mfma_f32_16x16x32_bf16(ld_frag(&wfrag[24 + mf*2    ][lane]), cb0, acc2[mf], 0, 0, 0);
    acc2[mf] = __builtin_amdgcn_mfma_f32_16x16x32_bf16(ld_frag(&wfrag[16 + mf*2 + 1][lane]), cb1, acc2[mf], 0, 0, 0);
    acc2[mf] = __builtin_amdgcn_mfma_f32_16x16x32_bf16(ld_frag(&wfrag[24 + mf*2 + 1][lane]), cb1, acc2[mf], 0, 0, 0);
  }

  // ---- + ob, transpose via LDS f32 tile [s][o], coalesced global store ----
  asm volatile("" ::: "memory");
  #pragma unroll
  for (int mf = 0; mf < 4; mf++) {
    int o0 = mf * 16 + 4 * g;
    float4 ob4 = *reinterpret_cast<const float4*>(ob + o0);
    float4 o4;
    o4.x = acc2[mf][0] + ob4.x;
    o4.y = acc2[mf][1] + ob4.y;
    o4.z = acc2[mf][2] + ob4.z;
    o4.w = acc2[mf][3] + ob4.w;
    *reinterpret_cast<float4*>(my + (c15 << 8) + (o0 << 2)) = o4;
  }
  asm volatile("" ::: "memory");
  {
    float4* op = reinterpret_cast<float4*>(out + rowbase);
    #pragma unroll
    for (int i = 0; i < 4; i++)
      op[qc + 4 * i] = *reinterpret_cast<const float4*>(my + (qr << 8) + ((qc + 4 * i) << 4));
  }
}

extern "C" void kernel_launch(void* const* d_in, const int* in_sizes, int n_in,
                              void* d_out, int out_size, void* d_ws, size_t ws_size,
                              hipStream_t stream)
{
  const float* act  = (const float*)d_in[0];
  const float* mask = (const float*)d_in[1];
  const float* lns  = (const float*)d_in[2];
  const float* lnb  = (const float*)d_in[3];
  const float* qw   = (const float*)d_in[4];
  const float* kw   = (const float*)d_in[5];
  const float* vw   = (const float*)d_in[6];
  const float* gw   = (const float*)d_in[7];
  const float* gb   = (const float*)d_in[8];
  const float* ow   = (const float*)d_in[9];
  const float* ob   = (const float*)d_in[10];

  float* wavg_ws = (float*)d_ws;                                   // 768*64 f32
  uint4* wsf     = (uint4*)((char*)d_ws + N_R * 64 * sizeof(float)); // 32 KiB frag tables

  stats_kernel<<<N_R + 1, 256, 0, stream>>>(act, mask, lns, lnb, qw, kw, vw,
                                            gw, ow, wavg_ws, wsf);
  proj_kernel<<<N_R * 16, 256, 0, stream>>>(act, lns, lnb, gb, ob,
                                            wavg_ws, (const uint4*)wsf, (float*)d_out);
}